// Round 13
// baseline (253.451 us; speedup 1.0000x reference)
//
#include <hip/hip_runtime.h>
#include <hip/hip_bf16.h>
#include <cstdint>
#include <cmath>

typedef __bf16 bf16_t;
typedef __attribute__((ext_vector_type(8))) bf16_t bf16x8;
typedef __attribute__((ext_vector_type(4))) float f32x4;

#define AS_GLOBAL(p) ((const __attribute__((address_space(1))) void*)(p))
#define AS_LDS(p)    ((__attribute__((address_space(3))) void*)(p))

// fp32 -> bf16 RTNE
__device__ __forceinline__ unsigned short f2bf(float f) {
  unsigned u = __builtin_bit_cast(unsigned, f);
  u += 0x7FFFu + ((u >> 16) & 1u);
  return (unsigned short)(u >> 16);
}

// ---------------- fused convert fp32 -> bf16 (x4 vectorized) ----------------
#define N4_X  2097152
#define N4_W  1048576
__global__ void cvt3_kernel(const float* __restrict__ x, const float* __restrict__ wq,
                            const float* __restrict__ wk, ushort4* __restrict__ xb4,
                            ushort4* __restrict__ wb4, float scale) {
  int i = blockIdx.x * blockDim.x + threadIdx.x;
  int stride = gridDim.x * blockDim.x;
  for (; i < N4_X + 2 * N4_W; i += stride) {
    const float4* src;
    ushort4* dst;
    float sc = 1.0f;
    if (i < N4_X) {
      src = reinterpret_cast<const float4*>(x) + i;
      dst = xb4 + i;
    } else if (i < N4_X + N4_W) {
      src = reinterpret_cast<const float4*>(wq) + (i - N4_X);
      dst = wb4 + (i - N4_X);
      sc = scale;
    } else {
      src = reinterpret_cast<const float4*>(wk) + (i - N4_X - N4_W);
      dst = wb4 + (i - N4_X);
    }
    float4 v = *src;
    ushort4 o;
    o.x = f2bf(v.x * sc);
    o.y = f2bf(v.y * sc);
    o.z = f2bf(v.z * sc);
    o.w = f2bf(v.w * sc);
    *dst = o;
  }
}

// ================= projection GEMM: 256x256 tile, 8-phase, read-once fragments (R9-proven) =================
#define PM 4096
#define PN 4096
#define PK 2048
#define PNT 32   // K tiles

template<int VM> __device__ __forceinline__ void waitcnt_vm() {
  if constexpr (VM == 0)  asm volatile("s_waitcnt vmcnt(0)" ::: "memory");
  else if constexpr (VM == 4)  asm volatile("s_waitcnt vmcnt(4)" ::: "memory");
  else if constexpr (VM == 6)  asm volatile("s_waitcnt vmcnt(6)" ::: "memory");
  else if constexpr (VM == 8)  asm volatile("s_waitcnt vmcnt(8)" ::: "memory");
  // VM < 0: no wait
}

// stage one 128x64 half-tile (16 KB): 2 x global_load_lds(16B) per thread
__device__ __forceinline__ void stage_half(const unsigned short* A, const unsigned short* B,
                                           int m0, int n0, int H, int wave, int lane,
                                           char* lds) {
  int tile = H >> 2;
  int mat  = H & 1;          // 0=A, 1=B
  int half = (H >> 1) & 1;
  int buf  = tile & 1;
  const unsigned short* src = mat ? B : A;
  int base0 = mat ? n0 : m0;
  char* hbase = lds + (((buf * 2 + mat) * 2 + half) * 16384);
  #pragma unroll
  for (int l = 0; l < 2; ++l) {
    int o = l * 8192 + wave * 1024 + lane * 16;
    int row = o >> 7;                  // 128B rows (BK=64 bf16)
    int c = o & 127;
    int csrc = c ^ ((row & 7) << 4);   // pre-swizzled global source
    const char* g = (const char*)(src + (size_t)(base0 + half * 128 + row) * PK)
                    + tile * 128 + csrc;
    __builtin_amdgcn_global_load_lds(AS_GLOBAL(g), AS_LDS(hbase + l * 8192 + wave * 1024),
                                     16, 0, 0);
  }
}

template<int Q, int VM>
__device__ __forceinline__ void phase(const unsigned short* A, const unsigned short* B,
                                      int m0, int n0, int T, int wave, int lane,
                                      int wm, int wn, char* lds, f32x4 (&acc)[8][4],
                                      bf16x8 (&av0)[4][2], bf16x8 (&av1)[4][2],
                                      bf16x8 (&bv0)[2][2], bf16x8 (&bv1)[2][2]) {
  constexpr int gm = Q >> 1, gn = Q & 1;
  const int buf = T & 1;
  const char* Ab = lds + (((buf * 2 + 0) * 2 + gm) * 16384);
  const char* Bb = lds + (((buf * 2 + 1) * 2 + gn) * 16384);

  bf16x8 (&av)[4][2] = (gm == 0) ? av0 : av1;
  bf16x8 (&bv)[2][2] = (gn == 0) ? bv0 : bv1;

  if constexpr (Q == 0 || Q == 2) {      // read this A-half once (8 x ds_read_b128)
    #pragma unroll
    for (int j = 0; j < 4; ++j) {
      int row = j * 32 + wm * 16 + (lane & 15);
      #pragma unroll
      for (int ks = 0; ks < 2; ++ks) {
        int kb = ks * 64 + (lane >> 4) * 16;
        av[j][ks] = *(const bf16x8*)(Ab + row * 128 + (kb ^ ((row & 7) << 4)));
      }
    }
  }
  if constexpr (Q == 0 || Q == 1) {      // read this B-half once (4 x ds_read_b128)
    #pragma unroll
    for (int i = 0; i < 2; ++i) {
      int row = i * 64 + wn * 16 + (lane & 15);
      #pragma unroll
      for (int ks = 0; ks < 2; ++ks) {
        int kb = ks * 64 + (lane >> 4) * 16;
        bv[i][ks] = *(const bf16x8*)(Bb + row * 128 + (kb ^ ((row & 7) << 4)));
      }
    }
  }

  int H = 4 * T + Q + 6;
  if (H < 4 * PNT) stage_half(A, B, m0, n0, H, wave, lane, lds);

  waitcnt_vm<VM>();
  asm volatile("s_barrier" ::: "memory");
  asm volatile("s_waitcnt lgkmcnt(0)" ::: "memory");
  __builtin_amdgcn_sched_barrier(0);

  __builtin_amdgcn_s_setprio(1);
  #pragma unroll
  for (int j = 0; j < 4; ++j)
    #pragma unroll
    for (int i = 0; i < 2; ++i)
      #pragma unroll
      for (int ks = 0; ks < 2; ++ks)
        acc[gm * 4 + j][gn * 2 + i] =
          __builtin_amdgcn_mfma_f32_16x16x32_bf16(av[j][ks], bv[i][ks],
                                                  acc[gm * 4 + j][gn * 2 + i], 0, 0, 0);
  __builtin_amdgcn_s_setprio(0);
  asm volatile("s_barrier" ::: "memory");
}

__global__ __launch_bounds__(512, 2) void proj_gemm(const unsigned short* __restrict__ A,
                                                    const unsigned short* __restrict__ Bm,
                                                    unsigned short* __restrict__ C) {
  __shared__ __align__(16) char lds[131072];
  const int tid = threadIdx.x;
  const int wave = tid >> 6, lane = tid & 63;
  const int wm = wave >> 2, wn = wave & 3;
  const int m0 = blockIdx.y * 256;
  const int n0 = blockIdx.x * 256;

  f32x4 acc[8][4] = {};
  bf16x8 av0[4][2], av1[4][2], bv0[2][2], bv1[2][2];

  #pragma unroll
  for (int h = 0; h < 6; ++h) stage_half(A, Bm, m0, n0, h, wave, lane, lds);
  waitcnt_vm<8>();
  asm volatile("s_barrier" ::: "memory");

  for (int T = 0; T < PNT - 2; ++T) {
    phase<0, 6>(A, Bm, m0, n0, T, wave, lane, wm, wn, lds, acc, av0, av1, bv0, bv1);
    phase<1, -1>(A, Bm, m0, n0, T, wave, lane, wm, wn, lds, acc, av0, av1, bv0, bv1);
    phase<2, -1>(A, Bm, m0, n0, T, wave, lane, wm, wn, lds, acc, av0, av1, bv0, bv1);
    phase<3, 8>(A, Bm, m0, n0, T, wave, lane, wm, wn, lds, acc, av0, av1, bv0, bv1);
  }
  phase<0, 6>(A, Bm, m0, n0, PNT - 2, wave, lane, wm, wn, lds, acc, av0, av1, bv0, bv1);
  phase<1, -1>(A, Bm, m0, n0, PNT - 2, wave, lane, wm, wn, lds, acc, av0, av1, bv0, bv1);
  phase<2, -1>(A, Bm, m0, n0, PNT - 2, wave, lane, wm, wn, lds, acc, av0, av1, bv0, bv1);
  phase<3, 4>(A, Bm, m0, n0, PNT - 2, wave, lane, wm, wn, lds, acc, av0, av1, bv0, bv1);
  phase<0, 0>(A, Bm, m0, n0, PNT - 1, wave, lane, wm, wn, lds, acc, av0, av1, bv0, bv1);
  phase<1, -1>(A, Bm, m0, n0, PNT - 1, wave, lane, wm, wn, lds, acc, av0, av1, bv0, bv1);
  phase<2, -1>(A, Bm, m0, n0, PNT - 1, wave, lane, wm, wn, lds, acc, av0, av1, bv0, bv1);
  phase<3, -1>(A, Bm, m0, n0, PNT - 1, wave, lane, wm, wn, lds, acc, av0, av1, bv0, bv1);

  #pragma unroll
  for (int f = 0; f < 8; ++f) {
    int rbase = m0 + (f >> 2) * 128 + (f & 3) * 32 + wm * 16 + (lane >> 4) * 4;
    #pragma unroll
    for (int nf = 0; nf < 4; ++nf) {
      int col = n0 + (nf >> 1) * 128 + (nf & 1) * 64 + wn * 16 + (lane & 15);
      #pragma unroll
      for (int r = 0; r < 4; ++r)
        C[(size_t)(rbase + r) * PN + col] = f2bf(acc[f][nf][r]);
    }
  }
}

// ---------------- scores kernel v9: QBLK=256 (2 qtiles), KVBLK=128, 512 threads ----------------
// Single mechanism vs R6-proven: each K staging pass now serves 256 q rows
// (2x K-reuse) -> K HBM re-fetch 268 MB -> 134 MB. 8 waves as 4(q) x 2(k);
// per-wave tile (64q x 64k), register footprint, MFMA/store pattern all
// IDENTICAL to the proven kernel. LDS 2 x 32 KB; grid 8 x 32 = 256 blocks.
__global__ __launch_bounds__(512) void scores_kernel(const unsigned short* __restrict__ qk,
                                                     float* __restrict__ out2) {
  __shared__ unsigned short Ks[2][128 * 128];
  const int tid = threadIdx.x;
  const int wave = tid >> 6, lane = tid & 63;
  const int qpair = blockIdx.x;          // 0..7: 256 q rows each
  const int bh = blockIdx.y;
  const int b = bh >> 4, h = bh & 15;
  const int wq = wave >> 1;              // 0..3: q-group (64 rows)
  const int wk2 = wave & 1;              // 0..1: k-group (64 cols)

  const unsigned short* qbase = qk + (size_t)(b * 2048 + qpair * 256) * 4096 + h * 128;
  const unsigned short* kbase = qk + (size_t)(b * 2048) * 4096 + 2048 + h * 128;

  // ---- Q fragments to registers (A-operand layout), loaded once ----
  bf16x8 qv[4][4];
  #pragma unroll
  for (int i = 0; i < 4; ++i) {
    int row = wq * 64 + i * 16 + (lane & 15);
    const unsigned short* qr = qbase + (size_t)row * 4096 + (lane >> 4) * 8;
    #pragma unroll
    for (int ks = 0; ks < 4; ++ks)
      qv[i][ks] = *(const bf16x8*)(qr + ks * 32);
  }

  // ---- stage K tile kt (128 rows x 256B = 32 KB): 4 issues/thread, 512 threads ----
  auto stageK = [&](int bi, int kt) {
    const unsigned short* kb = kbase + (size_t)kt * 128 * 4096;
    #pragma unroll
    for (int j = 0; j < 4; ++j) {
      int base = (wave * 4 + j) * 1024;     // 8 waves x 4 x 1KB = 32 KB
      int o = base + lane * 16;
      int row = o >> 8;                     // 256B rows (D=128 bf16)
      int c = o & 255;
      int csrc = c ^ ((row & 7) << 4);
      const char* gk = (const char*)(kb + (size_t)row * 4096) + csrc;
      __builtin_amdgcn_global_load_lds(AS_GLOBAL(gk), AS_LDS((char*)Ks[bi] + base), 16, 0, 0);
    }
  };

  float* obase = out2 + ((size_t)(b * 2048 + qpair * 256) * 16 + h) * 2048;
  const size_t qstride = (size_t)16 * 2048;

  stageK(0, 0);
  __syncthreads();

  int cur = 0;
  for (int kt = 0; kt < 16; ++kt) {
    if (kt + 1 < 16) stageK(cur ^ 1, kt + 1);

    f32x4 acc[4][4] = {};
    #pragma unroll
    for (int ks = 0; ks < 4; ++ks) {
      bf16x8 bv[4];
      const int kbyte = ks * 64 + (lane >> 4) * 16;
      #pragma unroll
      for (int j = 0; j < 4; ++j) {
        int row = wk2 * 64 + j * 16 + (lane & 15);
        int off = row * 256 + (kbyte ^ ((row & 7) << 4));
        bv[j] = *(const bf16x8*)((const char*)Ks[cur] + off);
      }
      #pragma unroll
      for (int i = 0; i < 4; ++i)
        #pragma unroll
        for (int j = 0; j < 4; ++j)
          acc[i][j] = __builtin_amdgcn_mfma_f32_16x16x32_bf16(qv[i][ks], bv[j], acc[i][j], 0, 0, 0);
    }

    __syncthreads();   // this iter's stage loads done; prev stores long in flight

    #pragma unroll
    for (int i = 0; i < 4; ++i)
      #pragma unroll
      for (int j = 0; j < 4; ++j)
        #pragma unroll
        for (int r = 0; r < 4; ++r) {
          int qrow = wq * 64 + i * 16 + (lane >> 4) * 4 + r;
          int col = kt * 128 + wk2 * 64 + j * 16 + (lane & 15);
          obase[(size_t)qrow * qstride + col] = acc[i][j][r];
        }

    cur ^= 1;
  }
}

extern "C" void kernel_launch(void* const* d_in, const int* in_sizes, int n_in,
                              void* d_out, int out_size, void* d_ws, size_t ws_size,
                              hipStream_t stream) {
  const float* x  = (const float*)d_in[0];
  const float* Wq = (const float*)d_in[1];
  const float* Wk = (const float*)d_in[2];
  // d_in[3] = Wv: computed then discarded by the reference -> skipped entirely.

  float* out = (float*)d_out;                             // fp32 output
  unsigned short* xb = (unsigned short*)d_ws;             // x as bf16      [4096][2048]
  unsigned short* wb = xb + (size_t)4096 * 2048;          // [Wq*scale; Wk] [4096][2048]
  unsigned short* qkbuf = wb + (size_t)4096 * 2048;       // Q||K           [4096][4096]

  const float scale = 1.0f / sqrtf(128.0f);

  // Output 0: attn_output = zeros, fp32, 2*2048*2048 elements (33.5 MB)
  hipMemsetAsync(d_out, 0, (size_t)2 * 2048 * 2048 * sizeof(float), stream);

  cvt3_kernel<<<2048, 256, 0, stream>>>(x, Wq, Wk, (ushort4*)xb, (ushort4*)wb, scale);

  proj_gemm<<<dim3(PN / 256, PM / 256), 512, 0, stream>>>(xb, wb, qkbuf);

  // Output 1: attn_weights fp32 at element offset 2*2048*2048
  scores_kernel<<<dim3(8, 32), 512, 0, stream>>>(qkbuf, out + (size_t)2 * 2048 * 2048);
}

// Round 14
// 249.235 us; speedup vs baseline: 1.0169x; 1.0169x over previous
//
#include <hip/hip_runtime.h>
#include <hip/hip_bf16.h>
#include <cstdint>
#include <cmath>

typedef __bf16 bf16_t;
typedef __attribute__((ext_vector_type(8))) bf16_t bf16x8;
typedef __attribute__((ext_vector_type(4))) float f32x4;

#define AS_GLOBAL(p) ((const __attribute__((address_space(1))) void*)(p))
#define AS_LDS(p)    ((__attribute__((address_space(3))) void*)(p))

// fp32 -> bf16 RTNE
__device__ __forceinline__ unsigned short f2bf(float f) {
  unsigned u = __builtin_bit_cast(unsigned, f);
  u += 0x7FFFu + ((u >> 16) & 1u);
  return (unsigned short)(u >> 16);
}

// ---------------- fused convert fp32 -> bf16 (x4 vectorized) ----------------
#define N4_X  2097152
#define N4_W  1048576
__global__ void cvt3_kernel(const float* __restrict__ x, const float* __restrict__ wq,
                            const float* __restrict__ wk, ushort4* __restrict__ xb4,
                            ushort4* __restrict__ wb4, float scale) {
  int i = blockIdx.x * blockDim.x + threadIdx.x;
  int stride = gridDim.x * blockDim.x;
  for (; i < N4_X + 2 * N4_W; i += stride) {
    const float4* src;
    ushort4* dst;
    float sc = 1.0f;
    if (i < N4_X) {
      src = reinterpret_cast<const float4*>(x) + i;
      dst = xb4 + i;
    } else if (i < N4_X + N4_W) {
      src = reinterpret_cast<const float4*>(wq) + (i - N4_X);
      dst = wb4 + (i - N4_X);
      sc = scale;
    } else {
      src = reinterpret_cast<const float4*>(wk) + (i - N4_X - N4_W);
      dst = wb4 + (i - N4_X);
    }
    float4 v = *src;
    ushort4 o;
    o.x = f2bf(v.x * sc);
    o.y = f2bf(v.y * sc);
    o.z = f2bf(v.z * sc);
    o.w = f2bf(v.w * sc);
    *dst = o;
  }
}

// ================= projection GEMM: 256x256 tile, 8-phase, read-once fragments (R9-proven) =================
#define PM 4096
#define PN 4096
#define PK 2048
#define PNT 32   // K tiles

template<int VM> __device__ __forceinline__ void waitcnt_vm() {
  if constexpr (VM == 0)  asm volatile("s_waitcnt vmcnt(0)" ::: "memory");
  else if constexpr (VM == 4)  asm volatile("s_waitcnt vmcnt(4)" ::: "memory");
  else if constexpr (VM == 6)  asm volatile("s_waitcnt vmcnt(6)" ::: "memory");
  else if constexpr (VM == 8)  asm volatile("s_waitcnt vmcnt(8)" ::: "memory");
  // VM < 0: no wait
}

// stage one 128x64 half-tile (16 KB): 2 x global_load_lds(16B) per thread
__device__ __forceinline__ void stage_half(const unsigned short* A, const unsigned short* B,
                                           int m0, int n0, int H, int wave, int lane,
                                           char* lds) {
  int tile = H >> 2;
  int mat  = H & 1;          // 0=A, 1=B
  int half = (H >> 1) & 1;
  int buf  = tile & 1;
  const unsigned short* src = mat ? B : A;
  int base0 = mat ? n0 : m0;
  char* hbase = lds + (((buf * 2 + mat) * 2 + half) * 16384);
  #pragma unroll
  for (int l = 0; l < 2; ++l) {
    int o = l * 8192 + wave * 1024 + lane * 16;
    int row = o >> 7;                  // 128B rows (BK=64 bf16)
    int c = o & 127;
    int csrc = c ^ ((row & 7) << 4);   // pre-swizzled global source
    const char* g = (const char*)(src + (size_t)(base0 + half * 128 + row) * PK)
                    + tile * 128 + csrc;
    __builtin_amdgcn_global_load_lds(AS_GLOBAL(g), AS_LDS(hbase + l * 8192 + wave * 1024),
                                     16, 0, 0);
  }
}

template<int Q, int VM>
__device__ __forceinline__ void phase(const unsigned short* A, const unsigned short* B,
                                      int m0, int n0, int T, int wave, int lane,
                                      int wm, int wn, char* lds, f32x4 (&acc)[8][4],
                                      bf16x8 (&av0)[4][2], bf16x8 (&av1)[4][2],
                                      bf16x8 (&bv0)[2][2], bf16x8 (&bv1)[2][2]) {
  constexpr int gm = Q >> 1, gn = Q & 1;
  const int buf = T & 1;
  const char* Ab = lds + (((buf * 2 + 0) * 2 + gm) * 16384);
  const char* Bb = lds + (((buf * 2 + 1) * 2 + gn) * 16384);

  bf16x8 (&av)[4][2] = (gm == 0) ? av0 : av1;
  bf16x8 (&bv)[2][2] = (gn == 0) ? bv0 : bv1;

  if constexpr (Q == 0 || Q == 2) {      // read this A-half once (8 x ds_read_b128)
    #pragma unroll
    for (int j = 0; j < 4; ++j) {
      int row = j * 32 + wm * 16 + (lane & 15);
      #pragma unroll
      for (int ks = 0; ks < 2; ++ks) {
        int kb = ks * 64 + (lane >> 4) * 16;
        av[j][ks] = *(const bf16x8*)(Ab + row * 128 + (kb ^ ((row & 7) << 4)));
      }
    }
  }
  if constexpr (Q == 0 || Q == 1) {      // read this B-half once (4 x ds_read_b128)
    #pragma unroll
    for (int i = 0; i < 2; ++i) {
      int row = i * 64 + wn * 16 + (lane & 15);
      #pragma unroll
      for (int ks = 0; ks < 2; ++ks) {
        int kb = ks * 64 + (lane >> 4) * 16;
        bv[i][ks] = *(const bf16x8*)(Bb + row * 128 + (kb ^ ((row & 7) << 4)));
      }
    }
  }

  int H = 4 * T + Q + 6;
  if (H < 4 * PNT) stage_half(A, B, m0, n0, H, wave, lane, lds);

  waitcnt_vm<VM>();
  asm volatile("s_barrier" ::: "memory");
  asm volatile("s_waitcnt lgkmcnt(0)" ::: "memory");
  __builtin_amdgcn_sched_barrier(0);

  __builtin_amdgcn_s_setprio(1);
  #pragma unroll
  for (int j = 0; j < 4; ++j)
    #pragma unroll
    for (int i = 0; i < 2; ++i)
      #pragma unroll
      for (int ks = 0; ks < 2; ++ks)
        acc[gm * 4 + j][gn * 2 + i] =
          __builtin_amdgcn_mfma_f32_16x16x32_bf16(av[j][ks], bv[i][ks],
                                                  acc[gm * 4 + j][gn * 2 + i], 0, 0, 0);
  __builtin_amdgcn_s_setprio(0);
  asm volatile("s_barrier" ::: "memory");
}

__global__ __launch_bounds__(512, 2) void proj_gemm(const unsigned short* __restrict__ A,
                                                    const unsigned short* __restrict__ Bm,
                                                    unsigned short* __restrict__ C) {
  __shared__ __align__(16) char lds[131072];
  const int tid = threadIdx.x;
  const int wave = tid >> 6, lane = tid & 63;
  const int wm = wave >> 2, wn = wave & 3;
  const int m0 = blockIdx.y * 256;
  const int n0 = blockIdx.x * 256;

  f32x4 acc[8][4] = {};
  bf16x8 av0[4][2], av1[4][2], bv0[2][2], bv1[2][2];

  #pragma unroll
  for (int h = 0; h < 6; ++h) stage_half(A, Bm, m0, n0, h, wave, lane, lds);
  waitcnt_vm<8>();
  asm volatile("s_barrier" ::: "memory");

  for (int T = 0; T < PNT - 2; ++T) {
    phase<0, 6>(A, Bm, m0, n0, T, wave, lane, wm, wn, lds, acc, av0, av1, bv0, bv1);
    phase<1, -1>(A, Bm, m0, n0, T, wave, lane, wm, wn, lds, acc, av0, av1, bv0, bv1);
    phase<2, -1>(A, Bm, m0, n0, T, wave, lane, wm, wn, lds, acc, av0, av1, bv0, bv1);
    phase<3, 8>(A, Bm, m0, n0, T, wave, lane, wm, wn, lds, acc, av0, av1, bv0, bv1);
  }
  phase<0, 6>(A, Bm, m0, n0, PNT - 2, wave, lane, wm, wn, lds, acc, av0, av1, bv0, bv1);
  phase<1, -1>(A, Bm, m0, n0, PNT - 2, wave, lane, wm, wn, lds, acc, av0, av1, bv0, bv1);
  phase<2, -1>(A, Bm, m0, n0, PNT - 2, wave, lane, wm, wn, lds, acc, av0, av1, bv0, bv1);
  phase<3, 4>(A, Bm, m0, n0, PNT - 2, wave, lane, wm, wn, lds, acc, av0, av1, bv0, bv1);
  phase<0, 0>(A, Bm, m0, n0, PNT - 1, wave, lane, wm, wn, lds, acc, av0, av1, bv0, bv1);
  phase<1, -1>(A, Bm, m0, n0, PNT - 1, wave, lane, wm, wn, lds, acc, av0, av1, bv0, bv1);
  phase<2, -1>(A, Bm, m0, n0, PNT - 1, wave, lane, wm, wn, lds, acc, av0, av1, bv0, bv1);
  phase<3, -1>(A, Bm, m0, n0, PNT - 1, wave, lane, wm, wn, lds, acc, av0, av1, bv0, bv1);

  #pragma unroll
  for (int f = 0; f < 8; ++f) {
    int rbase = m0 + (f >> 2) * 128 + (f & 3) * 32 + wm * 16 + (lane >> 4) * 4;
    #pragma unroll
    for (int nf = 0; nf < 4; ++nf) {
      int col = n0 + (nf >> 1) * 128 + (nf & 1) * 64 + wn * 16 + (lane & 15);
      #pragma unroll
      for (int r = 0; r < 4; ++r)
        C[(size_t)(rbase + r) * PN + col] = f2bf(acc[f][nf][r]);
    }
  }
}

// ---------------- scores kernel v10: QBLK=256 via 4 q-stacked waves, KVBLK=64, ksplit=2 ----------------
// K-reuse mechanism of R12 (K staged once per 256 q rows -> K HBM 268->134 MB)
// but occupancy-preserving: 256-thread blocks, LDS 2x16KB=32KB, ~170 VGPR ->
// grid dim3(8,32,2)=512 blocks = 2/CU (same inter-block overlap as proven R6).
// Per-wave shape (64q x 64k), staging idiom, ds_read/MFMA/store patterns all
// identical to proven code; only wave->q mapping (4q x 1k) and the column
// base (ksplit*1024 + kt*64) differ.
__global__ __launch_bounds__(256) void scores_kernel(const unsigned short* __restrict__ qk,
                                                     float* __restrict__ out2) {
  __shared__ unsigned short Ks[2][64 * 128];
  const int tid = threadIdx.x;
  const int wave = tid >> 6, lane = tid & 63;   // wave = q-group 0..3
  const int qblk = blockIdx.x;                  // 0..7: 256 q rows each
  const int bh = blockIdx.y;
  const int ksplit = blockIdx.z;                // 0..1: k columns [ksplit*1024, +1024)
  const int b = bh >> 4, h = bh & 15;

  const unsigned short* qbase = qk + (size_t)(b * 2048 + qblk * 256) * 4096 + h * 128;
  const unsigned short* kbase = qk + (size_t)(b * 2048 + ksplit * 1024) * 4096 + 2048 + h * 128;

  // ---- Q fragments to registers (A-operand layout), loaded once ----
  bf16x8 qv[4][4];
  #pragma unroll
  for (int i = 0; i < 4; ++i) {
    int row = wave * 64 + i * 16 + (lane & 15);
    const unsigned short* qr = qbase + (size_t)row * 4096 + (lane >> 4) * 8;
    #pragma unroll
    for (int ks = 0; ks < 4; ++ks)
      qv[i][ks] = *(const bf16x8*)(qr + ks * 32);
  }

  // ---- stage K tile kt (64 rows x 256B = 16 KB): 4 issues/thread ----
  auto stageK = [&](int bi, int kt) {
    const unsigned short* kb = kbase + (size_t)kt * 64 * 4096;
    #pragma unroll
    for (int j = 0; j < 4; ++j) {
      int base = (wave * 4 + j) * 1024;       // 4 waves x 4 KB = 16 KB
      int o = base + lane * 16;
      int row = o >> 8;                       // 256B rows (D=128 bf16)
      int c = o & 255;
      int csrc = c ^ ((row & 7) << 4);
      const char* gk = (const char*)(kb + (size_t)row * 4096) + csrc;
      __builtin_amdgcn_global_load_lds(AS_GLOBAL(gk), AS_LDS((char*)Ks[bi] + base), 16, 0, 0);
    }
  };

  float* obase = out2 + ((size_t)(b * 2048 + qblk * 256) * 16 + h) * 2048 + ksplit * 1024;
  const size_t qstride = (size_t)16 * 2048;

  stageK(0, 0);
  __syncthreads();

  int cur = 0;
  for (int kt = 0; kt < 16; ++kt) {
    if (kt + 1 < 16) stageK(cur ^ 1, kt + 1);

    f32x4 acc[4][4] = {};
    #pragma unroll
    for (int ks = 0; ks < 4; ++ks) {
      bf16x8 bv[4];
      const int kbyte = ks * 64 + (lane >> 4) * 16;
      #pragma unroll
      for (int j = 0; j < 4; ++j) {
        int row = j * 16 + (lane & 15);       // 64 k-rows of this tile
        int off = row * 256 + (kbyte ^ ((row & 7) << 4));
        bv[j] = *(const bf16x8*)((const char*)Ks[cur] + off);
      }
      #pragma unroll
      for (int i = 0; i < 4; ++i)
        #pragma unroll
        for (int j = 0; j < 4; ++j)
          acc[i][j] = __builtin_amdgcn_mfma_f32_16x16x32_bf16(qv[i][ks], bv[j], acc[i][j], 0, 0, 0);
    }

    __syncthreads();   // this iter's stage loads done; prev stores long in flight

    #pragma unroll
    for (int i = 0; i < 4; ++i)
      #pragma unroll
      for (int j = 0; j < 4; ++j)
        #pragma unroll
        for (int r = 0; r < 4; ++r) {
          int qrow = wave * 64 + i * 16 + (lane >> 4) * 4 + r;
          int col = kt * 64 + j * 16 + (lane & 15);
          obase[(size_t)qrow * qstride + col] = acc[i][j][r];
        }

    cur ^= 1;
  }
}

extern "C" void kernel_launch(void* const* d_in, const int* in_sizes, int n_in,
                              void* d_out, int out_size, void* d_ws, size_t ws_size,
                              hipStream_t stream) {
  const float* x  = (const float*)d_in[0];
  const float* Wq = (const float*)d_in[1];
  const float* Wk = (const float*)d_in[2];
  // d_in[3] = Wv: computed then discarded by the reference -> skipped entirely.

  float* out = (float*)d_out;                             // fp32 output
  unsigned short* xb = (unsigned short*)d_ws;             // x as bf16      [4096][2048]
  unsigned short* wb = xb + (size_t)4096 * 2048;          // [Wq*scale; Wk] [4096][2048]
  unsigned short* qkbuf = wb + (size_t)4096 * 2048;       // Q||K           [4096][4096]

  const float scale = 1.0f / sqrtf(128.0f);

  // Output 0: attn_output = zeros, fp32, 2*2048*2048 elements (33.5 MB)
  hipMemsetAsync(d_out, 0, (size_t)2 * 2048 * 2048 * sizeof(float), stream);

  cvt3_kernel<<<2048, 256, 0, stream>>>(x, Wq, Wk, (ushort4*)xb, (ushort4*)wb, scale);

  proj_gemm<<<dim3(PN / 256, PM / 256), 512, 0, stream>>>(xb, wb, qkbuf);

  // Output 1: attn_weights fp32 at element offset 2*2048*2048
  scores_kernel<<<dim3(8, 32, 2), 256, 0, stream>>>(qkbuf, out + (size_t)2 * 2048 * 2048);
}

// Round 15
// 225.153 us; speedup vs baseline: 1.1257x; 1.1070x over previous
//
#include <hip/hip_runtime.h>
#include <hip/hip_bf16.h>
#include <cstdint>
#include <cmath>

typedef __bf16 bf16_t;
typedef __attribute__((ext_vector_type(8))) bf16_t bf16x8;
typedef __attribute__((ext_vector_type(4))) float f32x4;

#define AS_GLOBAL(p) ((const __attribute__((address_space(1))) void*)(p))
#define AS_LDS(p)    ((__attribute__((address_space(3))) void*)(p))

// fp32 -> bf16 RTNE
__device__ __forceinline__ unsigned short f2bf(float f) {
  unsigned u = __builtin_bit_cast(unsigned, f);
  u += 0x7FFFu + ((u >> 16) & 1u);
  return (unsigned short)(u >> 16);
}

// ---------------- fused convert fp32 -> bf16 + zero-fill of attn_output ----------------
// Units: [0, N4_X): x float4->bf16x4 ; [N4_X, N4_X+2*N4_W): Wq|Wk ; then
// [.., +N4_Z): zero-fill out0 (float4). One dispatch replaces cvt3 + memset.
#define N4_X  2097152
#define N4_W  1048576
#define N4_Z  2097152   // 2*2048*2048 floats / 4
__global__ void cvt3z_kernel(const float* __restrict__ x, const float* __restrict__ wq,
                             const float* __restrict__ wk, ushort4* __restrict__ xb4,
                             ushort4* __restrict__ wb4, float4* __restrict__ zero4,
                             float scale) {
  int i = blockIdx.x * blockDim.x + threadIdx.x;
  int stride = gridDim.x * blockDim.x;
  const int total = N4_X + 2 * N4_W + N4_Z;
  for (; i < total; i += stride) {
    if (i < N4_X + 2 * N4_W) {
      const float4* src;
      ushort4* dst;
      float sc = 1.0f;
      if (i < N4_X) {
        src = reinterpret_cast<const float4*>(x) + i;
        dst = xb4 + i;
      } else if (i < N4_X + N4_W) {
        src = reinterpret_cast<const float4*>(wq) + (i - N4_X);
        dst = wb4 + (i - N4_X);
        sc = scale;
      } else {
        src = reinterpret_cast<const float4*>(wk) + (i - N4_X - N4_W);
        dst = wb4 + (i - N4_X);
      }
      float4 v = *src;
      ushort4 o;
      o.x = f2bf(v.x * sc);
      o.y = f2bf(v.y * sc);
      o.z = f2bf(v.z * sc);
      o.w = f2bf(v.w * sc);
      *dst = o;
    } else {
      zero4[i - (N4_X + 2 * N4_W)] = float4{0.f, 0.f, 0.f, 0.f};
    }
  }
}

// ================= projection GEMM: 256x256 tile, 8-phase, read-once fragments (R9-proven) =================
#define PM 4096
#define PN 4096
#define PK 2048
#define PNT 32   // K tiles

template<int VM> __device__ __forceinline__ void waitcnt_vm() {
  if constexpr (VM == 0)  asm volatile("s_waitcnt vmcnt(0)" ::: "memory");
  else if constexpr (VM == 4)  asm volatile("s_waitcnt vmcnt(4)" ::: "memory");
  else if constexpr (VM == 6)  asm volatile("s_waitcnt vmcnt(6)" ::: "memory");
  else if constexpr (VM == 8)  asm volatile("s_waitcnt vmcnt(8)" ::: "memory");
  // VM < 0: no wait
}

// stage one 128x64 half-tile (16 KB): 2 x global_load_lds(16B) per thread
__device__ __forceinline__ void stage_half(const unsigned short* A, const unsigned short* B,
                                           int m0, int n0, int H, int wave, int lane,
                                           char* lds) {
  int tile = H >> 2;
  int mat  = H & 1;          // 0=A, 1=B
  int half = (H >> 1) & 1;
  int buf  = tile & 1;
  const unsigned short* src = mat ? B : A;
  int base0 = mat ? n0 : m0;
  char* hbase = lds + (((buf * 2 + mat) * 2 + half) * 16384);
  #pragma unroll
  for (int l = 0; l < 2; ++l) {
    int o = l * 8192 + wave * 1024 + lane * 16;
    int row = o >> 7;                  // 128B rows (BK=64 bf16)
    int c = o & 127;
    int csrc = c ^ ((row & 7) << 4);   // pre-swizzled global source
    const char* g = (const char*)(src + (size_t)(base0 + half * 128 + row) * PK)
                    + tile * 128 + csrc;
    __builtin_amdgcn_global_load_lds(AS_GLOBAL(g), AS_LDS(hbase + l * 8192 + wave * 1024),
                                     16, 0, 0);
  }
}

template<int Q, int VM>
__device__ __forceinline__ void phase(const unsigned short* A, const unsigned short* B,
                                      int m0, int n0, int T, int wave, int lane,
                                      int wm, int wn, char* lds, f32x4 (&acc)[8][4],
                                      bf16x8 (&av0)[4][2], bf16x8 (&av1)[4][2],
                                      bf16x8 (&bv0)[2][2], bf16x8 (&bv1)[2][2]) {
  constexpr int gm = Q >> 1, gn = Q & 1;
  const int buf = T & 1;
  const char* Ab = lds + (((buf * 2 + 0) * 2 + gm) * 16384);
  const char* Bb = lds + (((buf * 2 + 1) * 2 + gn) * 16384);

  bf16x8 (&av)[4][2] = (gm == 0) ? av0 : av1;
  bf16x8 (&bv)[2][2] = (gn == 0) ? bv0 : bv1;

  if constexpr (Q == 0 || Q == 2) {      // read this A-half once (8 x ds_read_b128)
    #pragma unroll
    for (int j = 0; j < 4; ++j) {
      int row = j * 32 + wm * 16 + (lane & 15);
      #pragma unroll
      for (int ks = 0; ks < 2; ++ks) {
        int kb = ks * 64 + (lane >> 4) * 16;
        av[j][ks] = *(const bf16x8*)(Ab + row * 128 + (kb ^ ((row & 7) << 4)));
      }
    }
  }
  if constexpr (Q == 0 || Q == 1) {      // read this B-half once (4 x ds_read_b128)
    #pragma unroll
    for (int i = 0; i < 2; ++i) {
      int row = i * 64 + wn * 16 + (lane & 15);
      #pragma unroll
      for (int ks = 0; ks < 2; ++ks) {
        int kb = ks * 64 + (lane >> 4) * 16;
        bv[i][ks] = *(const bf16x8*)(Bb + row * 128 + (kb ^ ((row & 7) << 4)));
      }
    }
  }

  int H = 4 * T + Q + 6;
  if (H < 4 * PNT) stage_half(A, B, m0, n0, H, wave, lane, lds);

  waitcnt_vm<VM>();
  asm volatile("s_barrier" ::: "memory");
  asm volatile("s_waitcnt lgkmcnt(0)" ::: "memory");
  __builtin_amdgcn_sched_barrier(0);

  __builtin_amdgcn_s_setprio(1);
  #pragma unroll
  for (int j = 0; j < 4; ++j)
    #pragma unroll
    for (int i = 0; i < 2; ++i)
      #pragma unroll
      for (int ks = 0; ks < 2; ++ks)
        acc[gm * 4 + j][gn * 2 + i] =
          __builtin_amdgcn_mfma_f32_16x16x32_bf16(av[j][ks], bv[i][ks],
                                                  acc[gm * 4 + j][gn * 2 + i], 0, 0, 0);
  __builtin_amdgcn_s_setprio(0);
  asm volatile("s_barrier" ::: "memory");
}

__global__ __launch_bounds__(512, 2) void proj_gemm(const unsigned short* __restrict__ A,
                                                    const unsigned short* __restrict__ Bm,
                                                    unsigned short* __restrict__ C) {
  __shared__ __align__(16) char lds[131072];
  const int tid = threadIdx.x;
  const int wave = tid >> 6, lane = tid & 63;
  const int wm = wave >> 2, wn = wave & 3;
  const int m0 = blockIdx.y * 256;
  const int n0 = blockIdx.x * 256;

  f32x4 acc[8][4] = {};
  bf16x8 av0[4][2], av1[4][2], bv0[2][2], bv1[2][2];

  #pragma unroll
  for (int h = 0; h < 6; ++h) stage_half(A, Bm, m0, n0, h, wave, lane, lds);
  waitcnt_vm<8>();
  asm volatile("s_barrier" ::: "memory");

  for (int T = 0; T < PNT - 2; ++T) {
    phase<0, 6>(A, Bm, m0, n0, T, wave, lane, wm, wn, lds, acc, av0, av1, bv0, bv1);
    phase<1, -1>(A, Bm, m0, n0, T, wave, lane, wm, wn, lds, acc, av0, av1, bv0, bv1);
    phase<2, -1>(A, Bm, m0, n0, T, wave, lane, wm, wn, lds, acc, av0, av1, bv0, bv1);
    phase<3, 8>(A, Bm, m0, n0, T, wave, lane, wm, wn, lds, acc, av0, av1, bv0, bv1);
  }
  phase<0, 6>(A, Bm, m0, n0, PNT - 2, wave, lane, wm, wn, lds, acc, av0, av1, bv0, bv1);
  phase<1, -1>(A, Bm, m0, n0, PNT - 2, wave, lane, wm, wn, lds, acc, av0, av1, bv0, bv1);
  phase<2, -1>(A, Bm, m0, n0, PNT - 2, wave, lane, wm, wn, lds, acc, av0, av1, bv0, bv1);
  phase<3, 4>(A, Bm, m0, n0, PNT - 2, wave, lane, wm, wn, lds, acc, av0, av1, bv0, bv1);
  phase<0, 0>(A, Bm, m0, n0, PNT - 1, wave, lane, wm, wn, lds, acc, av0, av1, bv0, bv1);
  phase<1, -1>(A, Bm, m0, n0, PNT - 1, wave, lane, wm, wn, lds, acc, av0, av1, bv0, bv1);
  phase<2, -1>(A, Bm, m0, n0, PNT - 1, wave, lane, wm, wn, lds, acc, av0, av1, bv0, bv1);
  phase<3, -1>(A, Bm, m0, n0, PNT - 1, wave, lane, wm, wn, lds, acc, av0, av1, bv0, bv1);

  #pragma unroll
  for (int f = 0; f < 8; ++f) {
    int rbase = m0 + (f >> 2) * 128 + (f & 3) * 32 + wm * 16 + (lane >> 4) * 4;
    #pragma unroll
    for (int nf = 0; nf < 4; ++nf) {
      int col = n0 + (nf >> 1) * 128 + (nf & 1) * 64 + wn * 16 + (lane & 15);
      #pragma unroll
      for (int r = 0; r < 4; ++r)
        C[(size_t)(rbase + r) * PN + col] = f2bf(acc[f][nf][r]);
    }
  }
}

// ---------------- scores kernel v11: R6 geometry (QBLK=128, 2x2 waves), KVBLK=64 ----------------
// Single mechanism vs R6: K tile 128->64 rows => LDS 2x16KB=32KB and
// __launch_bounds__(256,3) => 3 blocks/CU (12 waves) instead of 2 (8 waves).
// K traffic UNCHANGED (reuse = QBLK, which stays 128 — R7's confound removed).
// Staging idiom = R7's proven 4-issue code; ds_read/MFMA/store = R6's with
// the j-range halved (wc*32).
__global__ __launch_bounds__(256, 3) void scores_kernel(const unsigned short* __restrict__ qk,
                                                        float* __restrict__ out2) {
  __shared__ unsigned short Ks[2][64 * 128];
  const int tid = threadIdx.x;
  const int wave = tid >> 6, lane = tid & 63;
  const int qtile = blockIdx.x;
  const int bh = blockIdx.y;
  const int b = bh >> 4, h = bh & 15;
  const int wr = wave >> 1, wc = wave & 1;

  const unsigned short* qbase = qk + (size_t)(b * 2048 + qtile * 128) * 4096 + h * 128;
  const unsigned short* kbase = qk + (size_t)(b * 2048) * 4096 + 2048 + h * 128;

  // ---- Q fragments to registers (A-operand layout), loaded once ----
  bf16x8 qv[4][4];
  #pragma unroll
  for (int i = 0; i < 4; ++i) {
    int row = wr * 64 + i * 16 + (lane & 15);
    const unsigned short* qr = qbase + (size_t)row * 4096 + (lane >> 4) * 8;
    #pragma unroll
    for (int ks = 0; ks < 4; ++ks)
      qv[i][ks] = *(const bf16x8*)(qr + ks * 32);
  }

  // ---- stage K tile kt (64 rows x 256B = 16 KB): 4 issues/thread (R7-proven) ----
  auto stageK = [&](int bi, int kt) {
    const unsigned short* kb = kbase + (size_t)kt * 64 * 4096;
    #pragma unroll
    for (int j = 0; j < 4; ++j) {
      int base = (wave * 4 + j) * 1024;
      int o = base + lane * 16;
      int row = o >> 8;                     // 256B rows (D=128 bf16)
      int c = o & 255;
      int csrc = c ^ ((row & 7) << 4);
      const char* gk = (const char*)(kb + (size_t)row * 4096) + csrc;
      __builtin_amdgcn_global_load_lds(AS_GLOBAL(gk), AS_LDS((char*)Ks[bi] + base), 16, 0, 0);
    }
  };

  float* obase = out2 + ((size_t)(b * 2048 + qtile * 128) * 16 + h) * 2048;
  const size_t qstride = (size_t)16 * 2048;

  stageK(0, 0);
  __syncthreads();

  int cur = 0;
  for (int kt = 0; kt < 32; ++kt) {
    if (kt + 1 < 32) stageK(cur ^ 1, kt + 1);

    f32x4 acc[4][2] = {};
    #pragma unroll
    for (int ks = 0; ks < 4; ++ks) {
      bf16x8 bv[2];
      const int kbyte = ks * 64 + (lane >> 4) * 16;
      #pragma unroll
      for (int j = 0; j < 2; ++j) {
        int row = wc * 32 + j * 16 + (lane & 15);
        int off = row * 256 + (kbyte ^ ((row & 7) << 4));
        bv[j] = *(const bf16x8*)((const char*)Ks[cur] + off);
      }
      #pragma unroll
      for (int i = 0; i < 4; ++i)
        #pragma unroll
        for (int j = 0; j < 2; ++j)
          acc[i][j] = __builtin_amdgcn_mfma_f32_16x16x32_bf16(qv[i][ks], bv[j], acc[i][j], 0, 0, 0);
    }

    __syncthreads();   // this iter's stage loads done; prev stores long in flight

    #pragma unroll
    for (int i = 0; i < 4; ++i)
      #pragma unroll
      for (int j = 0; j < 2; ++j)
        #pragma unroll
        for (int r = 0; r < 4; ++r) {
          int qrow = wr * 64 + i * 16 + (lane >> 4) * 4 + r;
          int col = kt * 64 + wc * 32 + j * 16 + (lane & 15);
          obase[(size_t)qrow * qstride + col] = acc[i][j][r];
        }

    cur ^= 1;
  }
}

extern "C" void kernel_launch(void* const* d_in, const int* in_sizes, int n_in,
                              void* d_out, int out_size, void* d_ws, size_t ws_size,
                              hipStream_t stream) {
  const float* x  = (const float*)d_in[0];
  const float* Wq = (const float*)d_in[1];
  const float* Wk = (const float*)d_in[2];
  // d_in[3] = Wv: computed then discarded by the reference -> skipped entirely.

  float* out = (float*)d_out;                             // fp32 output
  unsigned short* xb = (unsigned short*)d_ws;             // x as bf16      [4096][2048]
  unsigned short* wb = xb + (size_t)4096 * 2048;          // [Wq*scale; Wk] [4096][2048]
  unsigned short* qkbuf = wb + (size_t)4096 * 2048;       // Q||K           [4096][4096]

  const float scale = 1.0f / sqrtf(128.0f);

  // one dispatch: convert x/Wq/Wk AND zero-fill attn_output (out0)
  cvt3z_kernel<<<2048, 256, 0, stream>>>(x, Wq, Wk, (ushort4*)xb, (ushort4*)wb,
                                         (float4*)out, scale);

  proj_gemm<<<dim3(PN / 256, PM / 256), 512, 0, stream>>>(xb, wb, qkbuf);

  // Output 1: attn_weights fp32 at element offset 2*2048*2048
  scores_kernel<<<dim3(16, 32), 256, 0, stream>>>(qkbuf, out + (size_t)2 * 2048 * 2048);
}

// Round 16
// 222.745 us; speedup vs baseline: 1.1379x; 1.0108x over previous
//
#include <hip/hip_runtime.h>
#include <hip/hip_bf16.h>
#include <cstdint>
#include <cmath>

typedef __bf16 bf16_t;
typedef __attribute__((ext_vector_type(8))) bf16_t bf16x8;
typedef __attribute__((ext_vector_type(4))) float f32x4;

#define AS_GLOBAL(p) ((const __attribute__((address_space(1))) void*)(p))
#define AS_LDS(p)    ((__attribute__((address_space(3))) void*)(p))

// fp32 -> bf16 RTNE
__device__ __forceinline__ unsigned short f2bf(float f) {
  unsigned u = __builtin_bit_cast(unsigned, f);
  u += 0x7FFFu + ((u >> 16) & 1u);
  return (unsigned short)(u >> 16);
}

// ---------------- fused convert fp32 -> bf16 + zero-fill of attn_output (R14-proven) ----------------
#define N4_X  2097152
#define N4_W  1048576
#define N4_Z  2097152   // 2*2048*2048 floats / 4
__global__ void cvt3z_kernel(const float* __restrict__ x, const float* __restrict__ wq,
                             const float* __restrict__ wk, ushort4* __restrict__ xb4,
                             ushort4* __restrict__ wb4, float4* __restrict__ zero4,
                             float scale) {
  int i = blockIdx.x * blockDim.x + threadIdx.x;
  int stride = gridDim.x * blockDim.x;
  const int total = N4_X + 2 * N4_W + N4_Z;
  for (; i < total; i += stride) {
    if (i < N4_X + 2 * N4_W) {
      const float4* src;
      ushort4* dst;
      float sc = 1.0f;
      if (i < N4_X) {
        src = reinterpret_cast<const float4*>(x) + i;
        dst = xb4 + i;
      } else if (i < N4_X + N4_W) {
        src = reinterpret_cast<const float4*>(wq) + (i - N4_X);
        dst = wb4 + (i - N4_X);
        sc = scale;
      } else {
        src = reinterpret_cast<const float4*>(wk) + (i - N4_X - N4_W);
        dst = wb4 + (i - N4_X);
      }
      float4 v = *src;
      ushort4 o;
      o.x = f2bf(v.x * sc);
      o.y = f2bf(v.y * sc);
      o.z = f2bf(v.z * sc);
      o.w = f2bf(v.w * sc);
      *dst = o;
    } else {
      zero4[i - (N4_X + 2 * N4_W)] = float4{0.f, 0.f, 0.f, 0.f};
    }
  }
}

// ================= projection GEMM: 256x256 tile, 8-phase, read-once fragments (R9-proven) =================
#define PM 4096
#define PN 4096
#define PK 2048
#define PNT 32   // K tiles

template<int VM> __device__ __forceinline__ void waitcnt_vm() {
  if constexpr (VM == 0)  asm volatile("s_waitcnt vmcnt(0)" ::: "memory");
  else if constexpr (VM == 4)  asm volatile("s_waitcnt vmcnt(4)" ::: "memory");
  else if constexpr (VM == 6)  asm volatile("s_waitcnt vmcnt(6)" ::: "memory");
  else if constexpr (VM == 8)  asm volatile("s_waitcnt vmcnt(8)" ::: "memory");
  // VM < 0: no wait
}

// stage one 128x64 half-tile (16 KB): 2 x global_load_lds(16B) per thread
__device__ __forceinline__ void stage_half(const unsigned short* A, const unsigned short* B,
                                           int m0, int n0, int H, int wave, int lane,
                                           char* lds) {
  int tile = H >> 2;
  int mat  = H & 1;          // 0=A, 1=B
  int half = (H >> 1) & 1;
  int buf  = tile & 1;
  const unsigned short* src = mat ? B : A;
  int base0 = mat ? n0 : m0;
  char* hbase = lds + (((buf * 2 + mat) * 2 + half) * 16384);
  #pragma unroll
  for (int l = 0; l < 2; ++l) {
    int o = l * 8192 + wave * 1024 + lane * 16;
    int row = o >> 7;                  // 128B rows (BK=64 bf16)
    int c = o & 127;
    int csrc = c ^ ((row & 7) << 4);   // pre-swizzled global source
    const char* g = (const char*)(src + (size_t)(base0 + half * 128 + row) * PK)
                    + tile * 128 + csrc;
    __builtin_amdgcn_global_load_lds(AS_GLOBAL(g), AS_LDS(hbase + l * 8192 + wave * 1024),
                                     16, 0, 0);
  }
}

template<int Q, int VM>
__device__ __forceinline__ void phase(const unsigned short* A, const unsigned short* B,
                                      int m0, int n0, int T, int wave, int lane,
                                      int wm, int wn, char* lds, f32x4 (&acc)[8][4],
                                      bf16x8 (&av0)[4][2], bf16x8 (&av1)[4][2],
                                      bf16x8 (&bv0)[2][2], bf16x8 (&bv1)[2][2]) {
  constexpr int gm = Q >> 1, gn = Q & 1;
  const int buf = T & 1;
  const char* Ab = lds + (((buf * 2 + 0) * 2 + gm) * 16384);
  const char* Bb = lds + (((buf * 2 + 1) * 2 + gn) * 16384);

  bf16x8 (&av)[4][2] = (gm == 0) ? av0 : av1;
  bf16x8 (&bv)[2][2] = (gn == 0) ? bv0 : bv1;

  if constexpr (Q == 0 || Q == 2) {      // read this A-half once (8 x ds_read_b128)
    #pragma unroll
    for (int j = 0; j < 4; ++j) {
      int row = j * 32 + wm * 16 + (lane & 15);
      #pragma unroll
      for (int ks = 0; ks < 2; ++ks) {
        int kb = ks * 64 + (lane >> 4) * 16;
        av[j][ks] = *(const bf16x8*)(Ab + row * 128 + (kb ^ ((row & 7) << 4)));
      }
    }
  }
  if constexpr (Q == 0 || Q == 1) {      // read this B-half once (4 x ds_read_b128)
    #pragma unroll
    for (int i = 0; i < 2; ++i) {
      int row = i * 64 + wn * 16 + (lane & 15);
      #pragma unroll
      for (int ks = 0; ks < 2; ++ks) {
        int kb = ks * 64 + (lane >> 4) * 16;
        bv[i][ks] = *(const bf16x8*)(Bb + row * 128 + (kb ^ ((row & 7) << 4)));
      }
    }
  }

  int H = 4 * T + Q + 6;
  if (H < 4 * PNT) stage_half(A, B, m0, n0, H, wave, lane, lds);

  waitcnt_vm<VM>();
  asm volatile("s_barrier" ::: "memory");
  asm volatile("s_waitcnt lgkmcnt(0)" ::: "memory");
  __builtin_amdgcn_sched_barrier(0);

  __builtin_amdgcn_s_setprio(1);
  #pragma unroll
  for (int j = 0; j < 4; ++j)
    #pragma unroll
    for (int i = 0; i < 2; ++i)
      #pragma unroll
      for (int ks = 0; ks < 2; ++ks)
        acc[gm * 4 + j][gn * 2 + i] =
          __builtin_amdgcn_mfma_f32_16x16x32_bf16(av[j][ks], bv[i][ks],
                                                  acc[gm * 4 + j][gn * 2 + i], 0, 0, 0);
  __builtin_amdgcn_s_setprio(0);
  asm volatile("s_barrier" ::: "memory");
}

__global__ __launch_bounds__(512, 2) void proj_gemm(const unsigned short* __restrict__ A,
                                                    const unsigned short* __restrict__ Bm,
                                                    unsigned short* __restrict__ C) {
  __shared__ __align__(16) char lds[131072];
  const int tid = threadIdx.x;
  const int wave = tid >> 6, lane = tid & 63;
  const int wm = wave >> 2, wn = wave & 3;
  const int m0 = blockIdx.y * 256;
  const int n0 = blockIdx.x * 256;

  f32x4 acc[8][4] = {};
  bf16x8 av0[4][2], av1[4][2], bv0[2][2], bv1[2][2];

  #pragma unroll
  for (int h = 0; h < 6; ++h) stage_half(A, Bm, m0, n0, h, wave, lane, lds);
  waitcnt_vm<8>();
  asm volatile("s_barrier" ::: "memory");

  for (int T = 0; T < PNT - 2; ++T) {
    phase<0, 6>(A, Bm, m0, n0, T, wave, lane, wm, wn, lds, acc, av0, av1, bv0, bv1);
    phase<1, -1>(A, Bm, m0, n0, T, wave, lane, wm, wn, lds, acc, av0, av1, bv0, bv1);
    phase<2, -1>(A, Bm, m0, n0, T, wave, lane, wm, wn, lds, acc, av0, av1, bv0, bv1);
    phase<3, 8>(A, Bm, m0, n0, T, wave, lane, wm, wn, lds, acc, av0, av1, bv0, bv1);
  }
  phase<0, 6>(A, Bm, m0, n0, PNT - 2, wave, lane, wm, wn, lds, acc, av0, av1, bv0, bv1);
  phase<1, -1>(A, Bm, m0, n0, PNT - 2, wave, lane, wm, wn, lds, acc, av0, av1, bv0, bv1);
  phase<2, -1>(A, Bm, m0, n0, PNT - 2, wave, lane, wm, wn, lds, acc, av0, av1, bv0, bv1);
  phase<3, 4>(A, Bm, m0, n0, PNT - 2, wave, lane, wm, wn, lds, acc, av0, av1, bv0, bv1);
  phase<0, 0>(A, Bm, m0, n0, PNT - 1, wave, lane, wm, wn, lds, acc, av0, av1, bv0, bv1);
  phase<1, -1>(A, Bm, m0, n0, PNT - 1, wave, lane, wm, wn, lds, acc, av0, av1, bv0, bv1);
  phase<2, -1>(A, Bm, m0, n0, PNT - 1, wave, lane, wm, wn, lds, acc, av0, av1, bv0, bv1);
  phase<3, -1>(A, Bm, m0, n0, PNT - 1, wave, lane, wm, wn, lds, acc, av0, av1, bv0, bv1);

  #pragma unroll
  for (int f = 0; f < 8; ++f) {
    int rbase = m0 + (f >> 2) * 128 + (f & 3) * 32 + wm * 16 + (lane >> 4) * 4;
    #pragma unroll
    for (int nf = 0; nf < 4; ++nf) {
      int col = n0 + (nf >> 1) * 128 + (nf & 1) * 64 + wn * 16 + (lane & 15);
      #pragma unroll
      for (int r = 0; r < 4; ++r)
        C[(size_t)(rbase + r) * PN + col] = f2bf(acc[f][nf][r]);
    }
  }
}

// ---------------- scores kernel (R6-proven EXACT): persistent-Q, streaming-K, KVBLK=128 ----------------
// At its HBM-write roofline (~92 µs vs 87 µs floor): qkbuf L3-fits so K
// re-reads are cache-served; traffic = 537 MB write + first-touch. Seven
// restructures (sync order, tile shrink/grow, XCD swizzle, nontemporal, LDS
// drop, ksplit) all regressed or were neutral. Do not touch.
__global__ __launch_bounds__(256) void scores_kernel(const unsigned short* __restrict__ qk,
                                                     float* __restrict__ out2) {
  __shared__ unsigned short Ks[2][128 * 128];
  const int tid = threadIdx.x;
  const int wave = tid >> 6, lane = tid & 63;
  const int qtile = blockIdx.x;
  const int bh = blockIdx.y;
  const int b = bh >> 4, h = bh & 15;
  const int wr = wave >> 1, wc = wave & 1;

  const unsigned short* qbase = qk + (size_t)(b * 2048 + qtile * 128) * 4096 + h * 128;
  const unsigned short* kbase = qk + (size_t)(b * 2048) * 4096 + 2048 + h * 128;

  bf16x8 qv[4][4];
  #pragma unroll
  for (int i = 0; i < 4; ++i) {
    int row = wr * 64 + i * 16 + (lane & 15);
    const unsigned short* qr = qbase + (size_t)row * 4096 + (lane >> 4) * 8;
    #pragma unroll
    for (int ks = 0; ks < 4; ++ks)
      qv[i][ks] = *(const bf16x8*)(qr + ks * 32);
  }

  auto stageK = [&](int bi, int kt) {
    const unsigned short* kb = kbase + (size_t)kt * 128 * 4096;
    #pragma unroll
    for (int j = 0; j < 8; ++j) {
      int base = (wave * 8 + j) * 1024;
      int o = base + lane * 16;
      int row = o >> 8;
      int c = o & 255;
      int csrc = c ^ ((row & 7) << 4);
      const char* gk = (const char*)(kb + (size_t)row * 4096) + csrc;
      __builtin_amdgcn_global_load_lds(AS_GLOBAL(gk), AS_LDS((char*)Ks[bi] + base), 16, 0, 0);
    }
  };

  float* obase = out2 + ((size_t)(b * 2048 + qtile * 128) * 16 + h) * 2048;
  const size_t qstride = (size_t)16 * 2048;

  stageK(0, 0);
  __syncthreads();

  int cur = 0;
  for (int kt = 0; kt < 16; ++kt) {
    if (kt + 1 < 16) stageK(cur ^ 1, kt + 1);

    f32x4 acc[4][4] = {};
    #pragma unroll
    for (int ks = 0; ks < 4; ++ks) {
      bf16x8 bv[4];
      const int kbyte = ks * 64 + (lane >> 4) * 16;
      #pragma unroll
      for (int j = 0; j < 4; ++j) {
        int row = wc * 64 + j * 16 + (lane & 15);
        int off = row * 256 + (kbyte ^ ((row & 7) << 4));
        bv[j] = *(const bf16x8*)((const char*)Ks[cur] + off);
      }
      #pragma unroll
      for (int i = 0; i < 4; ++i)
        #pragma unroll
        for (int j = 0; j < 4; ++j)
          acc[i][j] = __builtin_amdgcn_mfma_f32_16x16x32_bf16(qv[i][ks], bv[j], acc[i][j], 0, 0, 0);
    }

    __syncthreads();

    #pragma unroll
    for (int i = 0; i < 4; ++i)
      #pragma unroll
      for (int j = 0; j < 4; ++j)
        #pragma unroll
        for (int r = 0; r < 4; ++r) {
          int qrow = wr * 64 + i * 16 + (lane >> 4) * 4 + r;
          int col = kt * 128 + wc * 64 + j * 16 + (lane & 15);
          obase[(size_t)qrow * qstride + col] = acc[i][j][r];
        }

    cur ^= 1;
  }
}

extern "C" void kernel_launch(void* const* d_in, const int* in_sizes, int n_in,
                              void* d_out, int out_size, void* d_ws, size_t ws_size,
                              hipStream_t stream) {
  const float* x  = (const float*)d_in[0];
  const float* Wq = (const float*)d_in[1];
  const float* Wk = (const float*)d_in[2];
  // d_in[3] = Wv: computed then discarded by the reference -> skipped entirely.

  float* out = (float*)d_out;                             // fp32 output
  unsigned short* xb = (unsigned short*)d_ws;             // x as bf16      [4096][2048]
  unsigned short* wb = xb + (size_t)4096 * 2048;          // [Wq*scale; Wk] [4096][2048]
  unsigned short* qkbuf = wb + (size_t)4096 * 2048;       // Q||K           [4096][4096]

  const float scale = 1.0f / sqrtf(128.0f);

  // one dispatch: convert x/Wq/Wk AND zero-fill attn_output (out0)
  cvt3z_kernel<<<2048, 256, 0, stream>>>(x, Wq, Wk, (ushort4*)xb, (ushort4*)wb,
                                         (float4*)out, scale);

  proj_gemm<<<dim3(PN / 256, PM / 256), 512, 0, stream>>>(xb, wb, qkbuf);

  // Output 1: attn_weights fp32 at element offset 2*2048*2048
  scores_kernel<<<dim3(16, 32), 256, 0, stream>>>(qkbuf, out + (size_t)2 * 2048 * 2048);
}